// Round 1
// baseline (508.952 us; speedup 1.0000x reference)
//
#include <hip/hip_runtime.h>
#include <math.h>

#define NQ_   32
#define M_    32
#define ND_   200
#define N_    160
#define H_    768
#define DIM_  128
#define DROWS_ (ND_ * N_)          // 32000
#define QROWS_ (NQ_ * M_)          // 1024
#define TROWS_ (DROWS_ + QROWS_)   // 33024

// async global->LDS, 16B per lane: LDS dest = wave-uniform base + lane*16
__device__ __forceinline__ void gl_lds16(const float* g, float* l) {
    __builtin_amdgcn_global_load_lds(
        (const __attribute__((address_space(1))) unsigned int*)g,
        (__attribute__((address_space(3))) unsigned int*)l, 16, 0, 0);
}

// ---------------------------------------------------------------------------
// Merged projection, double-buffered pipeline.
// Rows 0..31999 = D, 32000..33023 = Q. Tile 32 rows x 128 cols, 128 threads
// (2 waves), per-thread 4x8, K-chunk 16.
//   - W chunk (16x128 = 2048 contiguous floats) staged via global_load_lds
//     (4 calls/wave), issued one chunk AHEAD of its compute.
//   - X chunk reg-staged (1 float4/thread) one chunk ahead, ds_written just
//     before the barrier that publishes it.
//   => one __syncthreads per chunk; its vmcnt drain waits loads that were
//      issued a full compute-phase earlier (latency hidden).
// Epilogue: cross-row float4 stores (rows rg*4..+3 are consecutive n at a
// fixed k) -> 64B bursts instead of scattered 4B stores.
// FMA order identical to previous kernel (bit-exact outputs).
// ---------------------------------------------------------------------------
__global__ __launch_bounds__(128) void proj_kernel(
    const float* __restrict__ Dmat, const float* __restrict__ Qmat,
    const float* __restrict__ W, float* __restrict__ DpT,
    float* __restrict__ QpT)
{
    __shared__ __align__(16) float Xt[2][16][32];    // [buf][k][row]
    __shared__ __align__(16) float Ws[2][16][128];   // [buf][k][col]
    const int tid  = threadIdx.x;
    const int lane = tid & 63;
    const int wv   = tid >> 6;
    const int rb   = blockIdx.x * 32;
    const int cg   = tid & 15;       // col group: cols cg*8..+7
    const int rg   = tid >> 4;       // row group 0..7: rows rg*4..+3
    const int xrow = tid >> 2;       // staging row 0..31
    const int xc4  = tid & 3;        // staging k-quad

    const int rX = rb + xrow;
    const float* xr = (rX < DROWS_) ? (Dmat + (size_t)rX * H_)
                                    : (Qmat + (size_t)(rX - DROWS_) * H_);

    float acc[4][8];
#pragma unroll
    for (int i = 0; i < 4; ++i)
#pragma unroll
        for (int j = 0; j < 8; ++j) acc[i][j] = 0.0f;

    // prologue: issue chunk-0 staging
#pragma unroll
    for (int t = 0; t < 4; ++t) {
        const int part = wv * 4 + t;
        gl_lds16(W + part * 256 + lane * 4, &Ws[0][0][0] + part * 256);
    }
    float4 xreg = *reinterpret_cast<const float4*>(xr + xc4 * 4);

    for (int c = 0; c < 48; ++c) {
        const int cb = c & 1;
        // publish this chunk's X (compiler waits xreg's vmcnt here)
        Xt[cb][xc4*4+0][xrow] = xreg.x;
        Xt[cb][xc4*4+1][xrow] = xreg.y;
        Xt[cb][xc4*4+2][xrow] = xreg.z;
        Xt[cb][xc4*4+3][xrow] = xreg.w;
        __syncthreads();   // drains vmcnt (chunk-c W gl_lds) + lgkm, syncs waves
        if (c < 47) {      // issue chunk c+1 BEFORE computing chunk c
            const int kc = (c + 1) * 16;
            const float* wsrc = W + (size_t)kc * DIM_;
            float* wdst = &Ws[cb ^ 1][0][0];
#pragma unroll
            for (int t = 0; t < 4; ++t) {
                const int part = wv * 4 + t;
                gl_lds16(wsrc + part * 256 + lane * 4, wdst + part * 256);
            }
            xreg = *reinterpret_cast<const float4*>(xr + kc + xc4 * 4);
        }
        __builtin_amdgcn_sched_barrier(0);   // keep load issue above compute
#pragma unroll
        for (int k = 0; k < 16; ++k) {
            float a[4], b[8];
            *reinterpret_cast<float4*>(&a[0]) = *reinterpret_cast<const float4*>(&Xt[cb][k][rg*4]);
            *reinterpret_cast<float4*>(&b[0]) = *reinterpret_cast<const float4*>(&Ws[cb][k][cg*8]);
            *reinterpret_cast<float4*>(&b[4]) = *reinterpret_cast<const float4*>(&Ws[cb][k][cg*8+4]);
#pragma unroll
            for (int i = 0; i < 4; ++i)
#pragma unroll
                for (int j = 0; j < 8; ++j)
                    acc[i][j] = fmaf(a[i], b[j], acc[i][j]);
        }
    }

    // L2 norms: row r's 128 cols live in the 16 same-rg lanes (consecutive
    // lanes of one wave). Same reduce order as previous kernel.
    float nrm[4];
#pragma unroll
    for (int i = 0; i < 4; ++i) {
        float ss = 0.0f;
#pragma unroll
        for (int j = 0; j < 8; ++j) ss = __fadd_rn(ss, __fmul_rn(acc[i][j], acc[i][j]));
        ss = __fadd_rn(ss, __shfl_xor(ss, 1));
        ss = __fadd_rn(ss, __shfl_xor(ss, 2));
        ss = __fadd_rn(ss, __shfl_xor(ss, 4));
        ss = __fadd_rn(ss, __shfl_xor(ss, 8));
        nrm[i] = fmaxf(sqrtf(ss), 1e-12f);
    }

    if (rb < DROWS_) {
        const int dd = rb / 160, n0 = rb - dd * 160;   // 32-row blocks stay within one d
        float* o = DpT + (size_t)dd * (DIM_ * N_) + n0 + rg * 4;
#pragma unroll
        for (int j = 0; j < 8; ++j) {
            float4 v;
            v.x = acc[0][j] / nrm[0];
            v.y = acc[1][j] / nrm[1];
            v.z = acc[2][j] / nrm[2];
            v.w = acc[3][j] / nrm[3];
            *reinterpret_cast<float4*>(o + (size_t)(cg*8 + j) * N_) = v;
        }
    } else {
        const int rq = rb - DROWS_;
        const int qq = rq >> 5;
        float* o = QpT + (size_t)qq * (DIM_ * M_) + rg * 4;
#pragma unroll
        for (int j = 0; j < 8; ++j) {
            float4 v;
            v.x = acc[0][j] / nrm[0];
            v.y = acc[1][j] / nrm[1];
            v.z = acc[2][j] / nrm[2];
            v.w = acc[3][j] / nrm[3];
            *reinterpret_cast<float4*>(o + (size_t)(cg*8 + j) * M_) = v;
        }
    }
}

// ---------------------------------------------------------------------------
// Score: 128 threads (2 waves) per (q,d). grid 6400 (q fast for DpT reuse).
// K-chunk 8, double-buffered LDS (12.3 KB -> 13 blocks/CU), gl_lds staging
// split 3 calls/wave, issued one chunk ahead; one __syncthreads per chunk.
// Per-lane tile 4 rows x 10 cols (halves epilogue serial chain vs 8x10).
// Gumbel prefetched one row ahead. All per-(row,col) arithmetic and reduce
// orders identical to previous kernel; only the final 32-term m-sum is
// re-associated ((4+4)+(4+4) per wave, then wave0+wave1) — ~1e-6, outside
// the argmax path.
// ---------------------------------------------------------------------------
__global__ __launch_bounds__(128) void score_kernel(
    const float* __restrict__ QpT, const float* __restrict__ DpT,
    const float* __restrict__ qmask, const float* __restrict__ dmask,
    const float* __restrict__ gum, float* __restrict__ out)
{
    __shared__ __align__(16) float Qt[2][8][32];     // [buf][k][m]
    __shared__ __align__(16) float Dt[2][8][160];    // [buf][k][n]
    __shared__ float red[2];
    const int tid  = threadIdx.x;
    const int lane = tid & 63;
    const int wv   = tid >> 6;
    const int mg   = tid >> 4;      // 0..7: rows mg*4..+3
    const int ng   = tid & 15;      // cols ng*10..+9
    const int q    = blockIdx.x & 31;
    const int d    = blockIdx.x >> 5;   // 0..199

    const float* Qb = QpT + (size_t)q * (DIM_ * M_);
    const float* Db = DpT + (size_t)d * (DIM_ * N_);

    float acc[4][10];
#pragma unroll
    for (int i = 0; i < 4; ++i)
#pragma unroll
        for (int j = 0; j < 10; ++j) acc[i][j] = 0.0f;

    // prologue: issue chunk-0 staging (3 gl_lds per wave)
    if (wv == 0) {
        gl_lds16(Qb + lane * 4, &Qt[0][0][0]);
        gl_lds16(Db + lane * 4, &Dt[0][0][0]);
        gl_lds16(Db + 256 + lane * 4, &Dt[0][0][0] + 256);
    } else {
        gl_lds16(Db + 512  + lane * 4, &Dt[0][0][0] + 512);
        gl_lds16(Db + 768  + lane * 4, &Dt[0][0][0] + 768);
        gl_lds16(Db + 1024 + lane * 4, &Dt[0][0][0] + 1024);
    }

    for (int c = 0; c < 16; ++c) {
        const int cb = c & 1;
        __syncthreads();   // vmcnt drain = chunk-c loads (issued last iter)
        if (c < 15) {      // issue chunk c+1 before computing chunk c
            const float* qsrc = Qb + (size_t)(c + 1) * 8 * M_;
            const float* dsrc = Db + (size_t)(c + 1) * 8 * N_;
            float* qdst = &Qt[cb ^ 1][0][0];
            float* ddst = &Dt[cb ^ 1][0][0];
            if (wv == 0) {
                gl_lds16(qsrc + lane * 4, qdst);
                gl_lds16(dsrc + lane * 4, ddst);
                gl_lds16(dsrc + 256 + lane * 4, ddst + 256);
            } else {
                gl_lds16(dsrc + 512  + lane * 4, ddst + 512);
                gl_lds16(dsrc + 768  + lane * 4, ddst + 768);
                gl_lds16(dsrc + 1024 + lane * 4, ddst + 1024);
            }
        }
        __builtin_amdgcn_sched_barrier(0);   // keep load issue above compute
#pragma unroll
        for (int k = 0; k < 8; ++k) {
            float a[4], b[10];
            *reinterpret_cast<float4*>(&a[0]) = *reinterpret_cast<const float4*>(&Qt[cb][k][mg*4]);
            const float* bp = &Dt[cb][k][ng*10];    // conflict-free b64s
#pragma unroll
            for (int j2 = 0; j2 < 5; ++j2)
                *reinterpret_cast<float2*>(&b[j2*2]) = *reinterpret_cast<const float2*>(&bp[j2*2]);
#pragma unroll
            for (int i = 0; i < 4; ++i)
#pragma unroll
                for (int j = 0; j < 10; ++j)
                    acc[i][j] = fmaf(a[i], b[j], acc[i][j]);
        }
    }

    float dmv[10];
    {
        const float* dmp = dmask + (size_t)d * N_ + ng * 10;
#pragma unroll
        for (int j2 = 0; j2 < 5; ++j2)
            *reinterpret_cast<float2*>(&dmv[j2*2]) = *reinterpret_cast<const float2*>(&dmp[j2*2]);
    }

    const float* gq = gum + ((size_t)q * ND_ + d) * ((size_t)M_ * N_);

    // gumbel prefetch, one row ahead
    float g[2][10];
    {
        const float2* gp = reinterpret_cast<const float2*>(&gq[(size_t)(mg*4) * N_ + ng*10]);
#pragma unroll
        for (int j2 = 0; j2 < 5; ++j2)
            *reinterpret_cast<float2*>(&g[0][j2*2]) = gp[j2];
    }

    float partial = 0.0f;
#pragma unroll
    for (int i = 0; i < 4; ++i) {
        const int m = mg * 4 + i;
        float x[10];
        float mx = -3.402823466e38f;
#pragma unroll
        for (int j = 0; j < 10; ++j) {
            float sm = (dmv[j] != 0.0f) ? acc[i][j] : -10000.0f;
            x[j] = sm / 0.1f;                 // IEEE divide: bit-matches np
            mx = fmaxf(mx, x[j]);
        }
        if (i < 3) {   // issue next row's gumbel loads early
            const float2* gp = reinterpret_cast<const float2*>(&gq[(size_t)(m + 1) * N_ + ng*10]);
#pragma unroll
            for (int j2 = 0; j2 < 5; ++j2)
                *reinterpret_cast<float2*>(&g[(i+1)&1][j2*2]) = gp[j2];
        }
        mx = fmaxf(mx, __shfl_xor(mx, 1));
        mx = fmaxf(mx, __shfl_xor(mx, 2));
        mx = fmaxf(mx, __shfl_xor(mx, 4));
        mx = fmaxf(mx, __shfl_xor(mx, 8));

        float se = 0.0f;
#pragma unroll
        for (int j = 0; j < 10; ++j) se = __fadd_rn(se, expf(x[j] - mx));
        se = __fadd_rn(se, __shfl_xor(se, 1));
        se = __fadd_rn(se, __shfl_xor(se, 2));
        se = __fadd_rn(se, __shfl_xor(se, 4));
        se = __fadd_rn(se, __shfl_xor(se, 8));
        const float lse = logf(se);

        float z[10];
        float mz = -3.402823466e38f;
#pragma unroll
        for (int j = 0; j < 10; ++j) {
            z[j] = ((x[j] - mx - lse) + g[i&1][j]) / 0.5f;
            mz = fmaxf(mz, z[j]);
        }
        mz = fmaxf(mz, __shfl_xor(mz, 1));
        mz = fmaxf(mz, __shfl_xor(mz, 2));
        mz = fmaxf(mz, __shfl_xor(mz, 4));
        mz = fmaxf(mz, __shfl_xor(mz, 8));

        float e2[10];
        float s2 = 0.0f;
#pragma unroll
        for (int j = 0; j < 10; ++j) { e2[j] = expf(z[j] - mz); s2 = __fadd_rn(s2, e2[j]); }
        s2 = __fadd_rn(s2, __shfl_xor(s2, 1));
        s2 = __fadd_rn(s2, __shfl_xor(s2, 2));
        s2 = __fadd_rn(s2, __shfl_xor(s2, 4));
        s2 = __fadd_rn(s2, __shfl_xor(s2, 8));

        // argmax of y_soft = e2/s2 with numpy first-index tie-break
        float besty = -1.0f; int bestn = 0x7fffffff; float bests = 0.0f;
#pragma unroll
        for (int j = 0; j < 10; ++j) {
            float y = e2[j] / s2;
            if (y > besty) {
                besty = y;
                bestn = ng*10 + j;
                bests = (dmv[j] != 0.0f) ? acc[i][j] : -10000.0f;
            }
        }
#pragma unroll
        for (int dl = 1; dl < 16; dl <<= 1) {
            float oy = __shfl_xor(besty, dl);
            int   on = __shfl_xor(bestn, dl);
            float os = __shfl_xor(bests, dl);
            if (oy > besty || (oy == besty && on < bestn)) {
                besty = oy; bestn = on; bests = os;
            }
        }
        const float qmv = qmask[q * M_ + m];
        if (ng == 0) partial = __fadd_rn(partial, __fmul_rn(bests, qmv));
    }
    // per-wave: rows (mgA+mgB)+(mgC+mgD); then wave0(m0..15)+wave1(m16..31)
    partial = __fadd_rn(partial, __shfl_xor(partial, 16));
    partial = __fadd_rn(partial, __shfl_xor(partial, 32));
    if (lane == 0) red[wv] = partial;
    __syncthreads();
    if (tid == 0) out[(size_t)q * ND_ + d] = __fadd_rn(red[0], red[1]);
}

// ---------------------------------------------------------------------------
extern "C" void kernel_launch(void* const* d_in, const int* in_sizes, int n_in,
                              void* d_out, int out_size, void* d_ws, size_t ws_size,
                              hipStream_t stream)
{
    const float* Q   = (const float*)d_in[0];   // (32,32,768)
    const float* D   = (const float*)d_in[1];   // (200,160,768)
    const float* qm  = (const float*)d_in[2];   // (32,32)
    const float* dm  = (const float*)d_in[3];   // (200,160)
    const float* gum = (const float*)d_in[4];   // (32,200,32,160)
    const float* W   = (const float*)d_in[5];   // (768,128)
    float* out = (float*)d_out;                 // (32,200)

    float* QpT = (float*)d_ws;                          // 32*128*32   = 131072 floats
    float* DpT = QpT + (size_t)QROWS_ * DIM_;           // 200*128*160 = 4.096M floats

    proj_kernel<<<dim3(TROWS_ / 32), dim3(128), 0, stream>>>(D, Q, W, DpT, QpT);
    score_kernel<<<dim3(NQ_ * ND_), dim3(128), 0, stream>>>(QpT, DpT, qm, dm, gum, out);
}